// Round 4
// baseline (501.029 us; speedup 1.0000x reference)
//
#include <hip/hip_runtime.h>
#include <hip/hip_bf16.h>
#include <stdint.h>

#define B_DIM 256
#define I_DIM 128
#define C_DIM 1024
#define N_DIM 512              // U*S
#define KC    (C_DIM * I_DIM)
#define WC    (N_DIM * I_DIM)
#define BI    (B_DIM * I_DIM)  // 32768: xc row stride per c

typedef __bf16 bf16;
typedef __attribute__((ext_vector_type(8))) __bf16 bf16x8;
typedef __attribute__((ext_vector_type(4))) float f32x4;

__device__ __forceinline__ void async_copy16(const void* g, void* l) {
  __builtin_amdgcn_global_load_lds(
      (const __attribute__((address_space(1))) uint32_t*)g,
      (__attribute__((address_space(3))) uint32_t*)l, 16, 0, 0);
}

// ---------------------------------------------------------------------------
// Kernel 1: xc[c][b][i] = (bf16) x[b][i][c].  c-major layout: gemm A-tiles
// (fixed c, 128 b, all i) are dense 32-KB blocks.  64-MiB footprint.
// ---------------------------------------------------------------------------
__global__ void __launch_bounds__(256)
transpose_cast(const float* __restrict__ x, bf16* __restrict__ xc) {
  __shared__ float tile[64][65];
  const int c0 = blockIdx.x * 64;
  const int i0 = blockIdx.y * 64;
  const int b  = blockIdx.z;
  const int t  = threadIdx.x;
  const int sub = t >> 4;
  const int cg  = t & 15;
  const float* xb = x + (size_t)b * (I_DIM * C_DIM);
#pragma unroll
  for (int r = 0; r < 4; ++r) {
    const int i = r * 16 + sub;
    const float4 v = *(const float4*)&xb[(size_t)(i0 + i) * C_DIM + c0 + cg * 4];
    tile[i][cg * 4 + 0] = v.x; tile[i][cg * 4 + 1] = v.y;
    tile[i][cg * 4 + 2] = v.z; tile[i][cg * 4 + 3] = v.w;
  }
  __syncthreads();
#pragma unroll
  for (int r = 0; r < 2; ++r) {
    const int c  = r * 32 + (t >> 3);
    const int ic = (t & 7) * 8;
    bf16x8 o;
#pragma unroll
    for (int k = 0; k < 8; ++k) o[k] = (bf16)tile[ic + k][c];
    *(bf16x8*)&xc[(size_t)(c0 + c) * BI + (size_t)b * I_DIM + i0 + ic] = o;
  }
}

// ---------------------------------------------------------------------------
// Kernel 2: streaming split-K GEMM, ALL-DENSE staging (page-friendly HBM).
// Grid 256 = 2 mb (128 b) x 8 nb (64 n) x 16 c-chunks (64 c).  Decode puts a
// chunk's 16 blocks on ONE XCD: W tile dedup'd across the 2 mb-blocks,
// A tile across the 8 nb-blocks -> unique HBM = W 256 MB + A 64 MB.
// Step = one c: A = xc[c][mb*128+:128][:] 32 KB dense;
//               W = W[c][n0+:64][:] = 64 whole 512-B rows, 32 KB dense.
// Ring-2 (128 KB LDS), 8 async ops/thread/step, vmcnt(8): step t+1 in
// flight while computing t.  XOR ^(row&7) on source chunk AND read chunk:
// 2-way bank aliasing (free).
// ---------------------------------------------------------------------------
__device__ __forceinline__ void stage_step(
    const bf16* __restrict__ xc, const float* __restrict__ W,
    short* Asl, float* Wsl, int tid, int c, int mb, int n0) {
  // A: 128 rows x 16 chunks of 16 B, dense 32-KB source block.
  const size_t abase = (size_t)c * BI + (size_t)(mb * 128) * I_DIM;
#pragma unroll
  for (int p = 0; p < 4; ++p) {
    const int g  = p * 512 + tid;
    const int b  = g >> 4;                 // 0..127
    const int ch = (g & 15) ^ (b & 7);     // source-side swizzle
    async_copy16(xc + abase + (size_t)b * I_DIM + ch * 8, Asl + (size_t)g * 8);
  }
  // W: 64 rows x 32 chunks of 16 B, dense 32-KB source block.
  const size_t wbase = (size_t)c * WC + (size_t)n0 * I_DIM;
#pragma unroll
  for (int p = 0; p < 4; ++p) {
    const int g = p * 512 + tid;
    const int n = g >> 5;                  // 0..63
    const int q = (g & 31) ^ (n & 7);
    async_copy16(W + wbase + (size_t)n * I_DIM + q * 4, Wsl + (size_t)g * 4);
  }
}

__device__ __forceinline__ void compute_step(
    const short* As, const float* Wl,
    int wm, int wn, int l15, int lq, f32x4 (&acc)[2][2]) {
#pragma unroll
  for (int ksl = 0; ksl < 4; ++ksl) {
    bf16x8 a[2];
#pragma unroll
    for (int mt = 0; mt < 2; ++mt) {
      const int m  = wm * 32 + mt * 16 + l15;
      const int ch = (ksl * 4 + lq) ^ (m & 7);
      a[mt] = *(const bf16x8*)&As[m * 128 + ch * 8];
    }
    bf16x8 b[2];
#pragma unroll
    for (int nt = 0; nt < 2; ++nt) {
      const int n  = wn * 32 + nt * 16 + l15;
      const int q0 = (ksl * 8 + lq * 2)     ^ (n & 7);
      const int q1 = (ksl * 8 + lq * 2 + 1) ^ (n & 7);
      const f32x4 lo = *(const f32x4*)&Wl[n * 128 + q0 * 4];
      const f32x4 hi = *(const f32x4*)&Wl[n * 128 + q1 * 4];
      bf16x8 bb;
      bb[0] = (bf16)lo[0]; bb[1] = (bf16)lo[1];
      bb[2] = (bf16)lo[2]; bb[3] = (bf16)lo[3];
      bb[4] = (bf16)hi[0]; bb[5] = (bf16)hi[1];
      bb[6] = (bf16)hi[2]; bb[7] = (bf16)hi[3];
      b[nt] = bb;
    }
#pragma unroll
    for (int mt = 0; mt < 2; ++mt)
#pragma unroll
      for (int nt = 0; nt < 2; ++nt)
        acc[mt][nt] = __builtin_amdgcn_mfma_f32_16x16x32_bf16(
            a[mt], b[nt], acc[mt][nt], 0, 0, 0);
  }
}

__global__ void __launch_bounds__(512, 2)
gemm_kernel(const bf16* __restrict__ xc, const float* __restrict__ W,
            float* __restrict__ sj) {
  __shared__ short As[2][128 * I_DIM];   // 2 x 32 KB
  __shared__ float Wl[2][64 * I_DIM];    // 2 x 32 KB -> 128 KB total
  const int tid  = threadIdx.x;
  const int lane = tid & 63;
  const int wv   = tid >> 6;
  const int wm   = wv & 3;             // 0..3 -> m base wm*32 (within 128)
  const int wn   = wv >> 2;            // 0..1 -> n base wn*32 (within 64)
  const int l15  = lane & 15;
  const int lq   = lane >> 4;

  // bijective decode; chunk's 16 blocks (2 mb x 8 nb) share XCD = g&7.
  const int g     = blockIdx.x;
  const int s     = g >> 3;
  const int chunk = (g & 7) + 8 * (s >> 4);   // 0..15
  const int mb    = (s >> 3) & 1;
  const int nb    = s & 7;
  const int n0    = nb * 64;
  const int c0    = chunk * 64;

  f32x4 acc[2][2] = {};                // 16 acc regs

  // prologue: step 0 -> slot 0
  stage_step(xc, W, As[0], Wl[0], tid, c0, mb, n0);

#pragma unroll 1
  for (int t = 0; t < 63; ++t) {       // 64 steps = 64 c
    const int tn = t + 1;
    stage_step(xc, W, As[tn & 1], Wl[tn & 1], tid, c0 + tn, mb, n0);
    asm volatile("s_waitcnt vmcnt(8)" ::: "memory");   // step t landed
    __builtin_amdgcn_sched_barrier(0);
    __builtin_amdgcn_s_barrier();
    compute_step(As[t & 1], Wl[t & 1], wm, wn, l15, lq, acc);
    __builtin_amdgcn_s_barrier();      // slot reusable next iter
  }
  asm volatile("s_waitcnt vmcnt(0)" ::: "memory");
  __builtin_amdgcn_sched_barrier(0);
  __builtin_amdgcn_s_barrier();
  compute_step(As[1], Wl[1], wm, wn, l15, lq, acc);

  // epilogue: split-K partial -> sj (D layout: row = lq*4+r, col = l15)
#pragma unroll
  for (int mt = 0; mt < 2; ++mt) {
#pragma unroll
    for (int nt = 0; nt < 2; ++nt) {
      const int n = n0 + wn * 32 + nt * 16 + l15;
#pragma unroll
      for (int r = 0; r < 4; ++r) {
        const int brow = mb * 128 + wm * 32 + mt * 16 + lq * 4 + r;
        atomicAdd(&sj[(size_t)brow * N_DIM + n], acc[mt][nt][r]);
      }
    }
  }
}

// ---------------------------------------------------------------------------
// Kernel 3: squash.  per (b,s): msq = sum_u s^2 ; v = s * sqrt(msq)/(1+msq)
// ---------------------------------------------------------------------------
__global__ void __launch_bounds__(512)
squash_kernel(const float* __restrict__ sj, float* __restrict__ out) {
  __shared__ float sm[512];
  const int b = blockIdx.x;
  const int t = threadIdx.x;
  const float v = sj[(size_t)b * N_DIM + t];
  sm[t] = v * v;
  __syncthreads();
#pragma unroll
  for (int off = 256; off >= 16; off >>= 1) {
    if (t < off) sm[t] += sm[t + off];
    __syncthreads();
  }
  const float msq   = sm[t & 15];
  const float scale = sqrtf(msq) / (1.0f + msq);
  out[(size_t)b * N_DIM + t] = v * scale;
}

// ---------------------------------------------------------------------------
extern "C" void kernel_launch(void* const* d_in, const int* in_sizes, int n_in,
                              void* d_out, int out_size, void* d_ws, size_t ws_size,
                              hipStream_t stream) {
  const float* x = (const float*)d_in[0];   // (256,128,1024) fp32
  const float* W = (const float*)d_in[1];   // (1,1024,32,16,128) fp32
  float* out = (float*)d_out;               // (256,32,16,1) fp32

  bf16*  xc = (bf16*)d_ws;                                  // 64 MiB exactly
  float* sj = (float*)((char*)d_ws + (size_t)KC * B_DIM * sizeof(bf16));

  hipMemsetAsync(sj, 0, (size_t)B_DIM * N_DIM * sizeof(float), stream);
  transpose_cast<<<dim3(C_DIM / 64, I_DIM / 64, B_DIM), 256, 0, stream>>>(x, xc);
  gemm_kernel<<<dim3(256), 512, 0, stream>>>(xc, W, sj);
  squash_kernel<<<B_DIM, 512, 0, stream>>>(sj, out);
}